// Round 1
// baseline (30519.632 us; speedup 1.0000x reference)
//
#include <hip/hip_runtime.h>

// ---------------------------------------------------------------------------
// Persistent-kernel GRU: B=128, T=1024, I=256, H=1024, O=128.
// 256 WGs x 256 threads, 1 WG/CU (forced by 152KB LDS), 1025 grid barriers.
// W (bf16, MFMA B-frag swizzled) resident in LDS; h state fp32 in registers,
// broadcast as bf16 in MFMA A-frag layout ("hpack") through L2/LLC.
// ---------------------------------------------------------------------------

typedef __attribute__((ext_vector_type(8))) __bf16 bf16x8;
typedef __attribute__((ext_vector_type(4))) float floatx4;
typedef __attribute__((ext_vector_type(8))) unsigned short ushortx8;
typedef unsigned short ushort_t;
typedef unsigned int uint_t;

#define T_ 1024
#define I_ 256

// workspace layout (bytes)
#define NWPACK   3932160              // 64cg*40kb*3g*64lane*8 bf16 elems
#define NWOPACK  131072               // 8nt*32kb*64*8
#define HPACK_SLOT 131072             // 8mt*32kb*64*8 bf16 elems (=128x1024)
#define WPACK_OFF   0
#define WOPACK_OFF  (NWPACK*2)                       // 7,864,320
#define HPACK_OFF   (WOPACK_OFF + NWOPACK*2)         // 8,126,464
#define OUTPART_OFF (HPACK_OFF + 4*HPACK_SLOT*2)     // 9,175,040
#define BAR_OFF     (OUTPART_OFF + 131072*4)         // 9,699,328

__device__ __forceinline__ ushort_t f2bf(float f) {
    uint_t u = __float_as_uint(f);
    u += 0x7fffu + ((u >> 16) & 1u);
    return (ushort_t)(u >> 16);
}

__device__ __forceinline__ floatx4 mfma16(bf16x8 a, bf16x8 b, floatx4 c) {
    return __builtin_amdgcn_mfma_f32_16x16x32_bf16(a, b, c, 0, 0, 0);
}

// ---------------------------------------------------------------------------
// init: pack W_ih/W_hh into LDS-slice layout [cg][kb][gate][lane][8] bf16,
// W_out into [nt][kb][lane][8], zero hpack slot0 and the barrier page.
// ---------------------------------------------------------------------------
__global__ void gru_init(const float* __restrict__ W_ih, const float* __restrict__ W_hh,
                         const float* __restrict__ W_out,
                         ushort_t* __restrict__ wpack, ushort_t* __restrict__ wopack,
                         ushort_t* __restrict__ hpack0, uint_t* __restrict__ bar)
{
    const int total = NWPACK + NWOPACK + HPACK_SLOT/2 + 1024;
    for (int e = blockIdx.x * 256 + threadIdx.x; e < total; e += gridDim.x * 256) {
        if (e < NWPACK) {
            int j = e & 7;
            int lane = (e >> 3) & 63;
            int t2 = e >> 9;
            int g  = t2 % 3;
            int t3 = t2 / 3;
            int kb = t3 % 40;
            int cg = t3 / 40;
            int n = g * 1024 + cg * 16 + (lane & 15);
            int koff = ((lane >> 4) << 3) + j;
            float v;
            if (kb < 8) v = W_ih[(size_t)n * 256 + kb * 32 + koff];
            else        v = W_hh[(size_t)n * 1024 + (kb - 8) * 32 + koff];
            wpack[e] = f2bf(v);
        } else if (e < NWPACK + NWOPACK) {
            int e2 = e - NWPACK;
            int j = e2 & 7;
            int lane = (e2 >> 3) & 63;
            int kb = (e2 >> 9) & 31;
            int nt = e2 >> 14;
            int n = nt * 16 + (lane & 15);
            int k = kb * 32 + ((lane >> 4) << 3) + j;
            wopack[e2] = f2bf(W_out[(size_t)n * 1024 + k]);
        } else if (e < NWPACK + NWOPACK + HPACK_SLOT/2) {
            ((uint_t*)hpack0)[e - NWPACK - NWOPACK] = 0u;
        } else {
            bar[e - NWPACK - NWOPACK - HPACK_SLOT/2] = 0u;
        }
    }
}

// ---------------------------------------------------------------------------
// two-level grid barrier: 8 group counters (hashed blockIdx&7) -> root -> gen
// ---------------------------------------------------------------------------
__device__ __forceinline__ void grid_barrier(uint_t* bar, int bidx)
{
    __syncthreads();
    if (threadIdx.x == 0) {
        uint_t* gcnt = bar + (bidx & 7) * 64;
        uint_t* rcnt = bar + 512;
        uint_t* gen  = bar + 576;
        uint_t old = __hip_atomic_load(gen, __ATOMIC_RELAXED, __HIP_MEMORY_SCOPE_AGENT);
        uint_t a = __hip_atomic_fetch_add(gcnt, 1u, __ATOMIC_ACQ_REL, __HIP_MEMORY_SCOPE_AGENT);
        bool done = false;
        if (a == 31u) {
            uint_t r = __hip_atomic_fetch_add(rcnt, 1u, __ATOMIC_ACQ_REL, __HIP_MEMORY_SCOPE_AGENT);
            if (r == 7u) {
                for (int g = 0; g < 8; ++g)
                    __hip_atomic_store(bar + g * 64, 0u, __ATOMIC_RELAXED, __HIP_MEMORY_SCOPE_AGENT);
                __hip_atomic_store(rcnt, 0u, __ATOMIC_RELAXED, __HIP_MEMORY_SCOPE_AGENT);
                __hip_atomic_fetch_add(gen, 1u, __ATOMIC_RELEASE, __HIP_MEMORY_SCOPE_AGENT);
                done = true;
            }
        }
        if (!done) {
            while (__hip_atomic_load(gen, __ATOMIC_ACQUIRE, __HIP_MEMORY_SCOPE_AGENT) == old)
                __builtin_amdgcn_s_sleep(1);
        }
    }
    __syncthreads();
}

// ---------------------------------------------------------------------------
// main persistent kernel
// ---------------------------------------------------------------------------
__global__ void __launch_bounds__(256, 1)
gru_main(const float* __restrict__ seq,
         const float* __restrict__ b_ih, const float* __restrict__ b_hh,
         const float* __restrict__ b_out,
         const ushort_t* __restrict__ wpack, const ushort_t* __restrict__ wopack,
         ushort_t* __restrict__ hpack, float* __restrict__ outpart,
         uint_t* __restrict__ bar, float* __restrict__ dout)
{
    extern __shared__ char lds[];
    ushort_t* wlds = (ushort_t*)lds;            // [40][3][64][8] bf16 = 122880 B
    float*    xch  = (float*)(lds + 122880);    // [4][2][4][64][4] f32 = 32768 B

    const int w   = blockIdx.x;
    const int cg  = w & 63;       // h-column group (16 cols)
    const int m   = w >> 6;       // batch slice (32 rows)
    const int tid = threadIdx.x;
    const int wv  = tid >> 6;
    const int ln  = tid & 63;

    // stage this WG's weight slice into LDS (coalesced 16B)
    {
        const uint4* src = (const uint4*)(wpack + (size_t)cg * 61440);
        uint4* dst = (uint4*)lds;
        for (int i = tid; i < 7680; i += 256) dst[i] = src[i];
    }

    float bihr = 0, bhhr = 0, bihz = 0, bhhz = 0, bihn = 0, bhhn = 0;
    if (wv < 2) {
        int col = cg * 16 + (ln & 15);
        bihr = b_ih[col];          bhhr = b_hh[col];
        bihz = b_ih[1024 + col];   bhhz = b_hh[1024 + col];
        bihn = b_ih[2048 + col];   bhhn = b_hh[2048 + col];
    }
    float bo0 = 0, bo1 = 0;
    if (wv == 3 && w < 128) { bo0 = b_out[ln]; bo1 = b_out[ln + 64]; }

    floatx4 hold = {0.f, 0.f, 0.f, 0.f};   // fp32 authoritative h slice (reducers)

    const int omt = w & 7, ont = (w >> 3) & 7, oks = w >> 6;  // out-proj job
    const int kb0 = wv * 10;
    const int mtb0 = m * 2, mtb1 = m * 2 + 1;

    __syncthreads();

#define XSLOT(sw, mt, g) (xch + (((sw) * 2 + (mt)) * 4 + (g)) * 256 + ln * 4)

    for (int it = 0; it < 1025; ++it) {
        const ushort_t* hcur = hpack + (size_t)(it & 3) * HPACK_SLOT;

        floatx4 accr0 = {0,0,0,0}, accr1 = {0,0,0,0};
        floatx4 accz0 = {0,0,0,0}, accz1 = {0,0,0,0};
        floatx4 acch0 = {0,0,0,0}, acch1 = {0,0,0,0};
        floatx4 acci0 = {0,0,0,0}, acci1 = {0,0,0,0};

        if (it <= 1022) {
            #pragma unroll
            for (int ki = 0; ki < 10; ++ki) {
                const int kb = kb0 + ki;
                bf16x8 a0, a1;
                if (kb < 8) {
                    // x_t fp32 -> bf16 on the fly (A-frag layout)
                    int koffx = kb * 32 + ((ln >> 4) << 3);
                    const float* p0 = seq + (size_t)(mtb0 * 16 + (ln & 15)) * (T_ * I_)
                                          + (size_t)it * I_ + koffx;
                    const float* p1 = p0 + (size_t)16 * (T_ * I_);
                    float4 fa = *(const float4*)p0, fb = *(const float4*)(p0 + 4);
                    float4 ga = *(const float4*)p1, gb = *(const float4*)(p1 + 4);
                    ushortx8 u0, u1;
                    u0[0] = f2bf(fa.x); u0[1] = f2bf(fa.y); u0[2] = f2bf(fa.z); u0[3] = f2bf(fa.w);
                    u0[4] = f2bf(fb.x); u0[5] = f2bf(fb.y); u0[6] = f2bf(fb.z); u0[7] = f2bf(fb.w);
                    u1[0] = f2bf(ga.x); u1[1] = f2bf(ga.y); u1[2] = f2bf(ga.z); u1[3] = f2bf(ga.w);
                    u1[4] = f2bf(gb.x); u1[5] = f2bf(gb.y); u1[6] = f2bf(gb.z); u1[7] = f2bf(gb.w);
                    a0 = __builtin_bit_cast(bf16x8, u0);
                    a1 = __builtin_bit_cast(bf16x8, u1);
                } else {
                    a0 = *(const bf16x8*)(hcur + (((size_t)mtb0 * 32 + (kb - 8)) * 64 + ln) * 8);
                    a1 = *(const bf16x8*)(hcur + (((size_t)mtb1 * 32 + (kb - 8)) * 64 + ln) * 8);
                }
                const bf16x8 br = *(const bf16x8*)(wlds + ((kb * 3 + 0) * 64 + ln) * 8);
                const bf16x8 bz = *(const bf16x8*)(wlds + ((kb * 3 + 1) * 64 + ln) * 8);
                const bf16x8 bn = *(const bf16x8*)(wlds + ((kb * 3 + 2) * 64 + ln) * 8);
                accr0 = mfma16(a0, br, accr0);  accr1 = mfma16(a1, br, accr1);
                accz0 = mfma16(a0, bz, accz0);  accz1 = mfma16(a1, bz, accz1);
                if (kb < 8) { acci0 = mfma16(a0, bn, acci0); acci1 = mfma16(a1, bn, acci1); }
                else        { acch0 = mfma16(a0, bn, acch0); acch1 = mfma16(a1, bn, acch1); }
            }
            // exchange partial accumulators via LDS
            if (wv == 0) {
                *(floatx4*)XSLOT(0, 1, 0) = accr1; *(floatx4*)XSLOT(0, 1, 1) = accz1;
                *(floatx4*)XSLOT(0, 1, 2) = acch1; *(floatx4*)XSLOT(0, 1, 3) = acci1;
            } else if (wv == 1) {
                *(floatx4*)XSLOT(1, 0, 0) = accr0; *(floatx4*)XSLOT(1, 0, 1) = accz0;
                *(floatx4*)XSLOT(1, 0, 2) = acch0;
            } else {
                *(floatx4*)XSLOT(wv, 0, 0) = accr0; *(floatx4*)XSLOT(wv, 0, 1) = accz0;
                *(floatx4*)XSLOT(wv, 0, 2) = acch0;
                *(floatx4*)XSLOT(wv, 1, 0) = accr1; *(floatx4*)XSLOT(wv, 1, 1) = accz1;
                *(floatx4*)XSLOT(wv, 1, 2) = acch1;
            }
        }
        __syncthreads();

        // reducers: gate math, h update (fp32 regs), write bf16 hpack
        if (it <= 1022 && wv < 2) {
            const int mtr = wv;
            floatx4 r  = (mtr == 0) ? accr0 : accr1;
            floatx4 z  = (mtr == 0) ? accz0 : accz1;
            floatx4 hn = (mtr == 0) ? acch0 : acch1;
            floatx4 inn = (wv == 0) ? acci0 : *(floatx4*)XSLOT(0, 1, 3);
            #pragma unroll
            for (int sw = 0; sw < 4; ++sw) {
                if (sw == wv) continue;
                r  += *(floatx4*)XSLOT(sw, mtr, 0);
                z  += *(floatx4*)XSLOT(sw, mtr, 1);
                hn += *(floatx4*)XSLOT(sw, mtr, 2);
            }
            ushort_t* hnew = hpack + (size_t)((it + 1) & 3) * HPACK_SLOT;
            const int mtW = m * 2 + mtr;
            const int kbh = cg >> 1;
            const int koffb = ((cg & 1) << 4) + (ln & 15);
            const int lanep = (koffb >> 3) << 4;
            const int jj = koffb & 7;
            const int rbase = (ln >> 4) * 4;
            #pragma unroll
            for (int e = 0; e < 4; ++e) {
                float rp = r[e] + bihr + bhhr;
                float rg = 1.f / (1.f + __expf(-rp));
                float zp = z[e] + bihz + bhhz;
                float zg = 1.f / (1.f + __expf(-zp));
                float nx = inn[e] + bihn + rg * (hn[e] + bhhn);
                float ng = 1.f - 2.f / (__expf(2.f * nx) + 1.f);
                float hv = (1.f - zg) * ng + zg * hold[e];
                hold[e] = hv;
                size_t idx = (((size_t)mtW * 32 + kbh) * 64 + (unsigned)((rbase + e) | lanep)) * 8 + jj;
                hnew[idx] = f2bf(hv);
            }
        }

        // wave2: out-projection partial for h_it (one step behind gates)
        if (wv == 2 && it >= 1 && it <= 1023) {
            const ushort_t* hh = hpack + (size_t)(it & 3) * HPACK_SLOT;
            floatx4 acc = {0, 0, 0, 0};
            #pragma unroll
            for (int i2 = 0; i2 < 8; ++i2) {
                int kb = oks * 8 + i2;
                bf16x8 a = *(const bf16x8*)(hh + (((size_t)omt * 32 + kb) * 64 + ln) * 8);
                bf16x8 b = *(const bf16x8*)(wopack + (((size_t)ont * 32 + kb) * 64 + ln) * 8);
                acc = mfma16(a, b, acc);
            }
            float* op = outpart + (size_t)(it & 1) * 65536 + (size_t)oks * 16384;
            int colo = ont * 16 + (ln & 15);
            #pragma unroll
            for (int e = 0; e < 4; ++e) {
                int rowo = omt * 16 + (ln >> 4) * 4 + e;
                op[rowo * 128 + colo] = acc[e];
            }
        }

        // wave3: finalize log_softmax for h_{it-1} (two steps behind gates)
        if (wv == 3 && w < 128 && it >= 2) {
            const float* op = outpart + (size_t)((it - 1) & 1) * 65536;
            float v0 = bo0, v1 = bo1;
            #pragma unroll
            for (int ks2 = 0; ks2 < 4; ++ks2) {
                v0 += op[ks2 * 16384 + w * 128 + ln];
                v1 += op[ks2 * 16384 + w * 128 + ln + 64];
            }
            float mx = fmaxf(v0, v1);
            #pragma unroll
            for (int off = 32; off >= 1; off >>= 1) mx = fmaxf(mx, __shfl_xor(mx, off));
            float e0 = __expf(v0 - mx), e1 = __expf(v1 - mx);
            float sm = e0 + e1;
            #pragma unroll
            for (int off = 32; off >= 1; off >>= 1) sm += __shfl_xor(sm, off);
            float lse = mx + __logf(sm);
            float* po = dout + ((size_t)w * 1023 + (it - 2)) * 128;
            po[ln] = v0 - lse;
            po[ln + 64] = v1 - lse;
        }

        grid_barrier(bar, w);
    }
#undef XSLOT
}

// ---------------------------------------------------------------------------
extern "C" void kernel_launch(void* const* d_in, const int* in_sizes, int n_in,
                              void* d_out, int out_size, void* d_ws, size_t ws_size,
                              hipStream_t stream)
{
    const float* seq  = (const float*)d_in[0];
    const float* Wih  = (const float*)d_in[1];
    const float* Whh  = (const float*)d_in[2];
    const float* bih  = (const float*)d_in[3];
    const float* bhh  = (const float*)d_in[4];
    const float* Wout = (const float*)d_in[5];
    const float* bout = (const float*)d_in[6];

    char* ws = (char*)d_ws;
    ushort_t* wpack   = (ushort_t*)(ws + WPACK_OFF);
    ushort_t* wopack  = (ushort_t*)(ws + WOPACK_OFF);
    ushort_t* hpack   = (ushort_t*)(ws + HPACK_OFF);
    float*    outpart = (float*)(ws + OUTPART_OFF);
    uint_t*   bar     = (uint_t*)(ws + BAR_OFF);

    gru_init<<<1024, 256, 0, stream>>>(Wih, Whh, Wout, wpack, wopack, hpack, bar);

    hipFuncSetAttribute((const void*)gru_main,
                        hipFuncAttributeMaxDynamicSharedMemorySize, 155648);
    gru_main<<<256, 256, 155648, stream>>>(seq, bih, bhh, bout, wpack, wopack,
                                           hpack, outpart, bar, (float*)d_out);
}

// Round 2
// 9503.786 us; speedup vs baseline: 3.2113x; 3.2113x over previous
//
#include <hip/hip_runtime.h>

// ---------------------------------------------------------------------------
// Persistent-kernel GRU: B=128, T=1024, I=256, H=1024, O=128.
// 256 WGs x 256 threads, 1 WG/CU. Four INDEPENDENT batch-groups of 64 WGs,
// each with its own monotone-counter barrier (relaxed atomics only — no
// acquire/release fences -> no buffer_wbl2 / buffer_inv storms).
// Cross-WG data (h ring, out-proj partials) moves through the LLC via
// agent-scope relaxed atomic loads/stores (global_* sc1 — cache-bypass bits,
// full-rate instructions). W (bf16, MFMA B-frag swizzled) resident in LDS.
// ---------------------------------------------------------------------------

typedef __attribute__((ext_vector_type(8))) __bf16 bf16x8;
typedef __attribute__((ext_vector_type(4))) float floatx4;
typedef __attribute__((ext_vector_type(8))) unsigned short ushortx8;
typedef unsigned short ushort_t;
typedef unsigned int uint_t;
typedef unsigned long long ull_t;

#define T_ 1024
#define I_ 256

// workspace layout (bytes)
#define NWPACK   3932160              // 64cg*40kb*3g*64lane*8 bf16 elems
#define NWOPACK  131072               // 8nt*32kb*64*8
#define HPACK_SLOT 131072             // 8mt*32kb*64*8 bf16 elems (=128x1024)
#define WPACK_OFF   0
#define WOPACK_OFF  (NWPACK*2)                       // 7,864,320
#define HPACK_OFF   (WOPACK_OFF + NWOPACK*2)         // 8,126,464
#define OUTPART_OFF (HPACK_OFF + 4*HPACK_SLOT*2)     // 9,175,040
#define BAR_OFF     (OUTPART_OFF + 131072*4)         // 9,699,328

__device__ __forceinline__ ushort_t f2bf(float f) {
    uint_t u = __float_as_uint(f);
    u += 0x7fffu + ((u >> 16) & 1u);
    return (ushort_t)(u >> 16);
}

__device__ __forceinline__ floatx4 mfma16(bf16x8 a, bf16x8 b, floatx4 c) {
    return __builtin_amdgcn_mfma_f32_16x16x32_bf16(a, b, c, 0, 0, 0);
}

// LLC-coherent (sc1) 16B fragment load as 2x8B relaxed agent atomics
__device__ __forceinline__ bf16x8 ld_llc16(const ushort_t* p) {
    union { ull_t q[2]; bf16x8 v; } u;
    u.q[0] = __hip_atomic_load((const ull_t*)p,     __ATOMIC_RELAXED, __HIP_MEMORY_SCOPE_AGENT);
    u.q[1] = __hip_atomic_load((const ull_t*)p + 1, __ATOMIC_RELAXED, __HIP_MEMORY_SCOPE_AGENT);
    return u.v;
}
__device__ __forceinline__ void st_llc2(ushort_t* p, ushort_t v) {
    __hip_atomic_store(p, v, __ATOMIC_RELAXED, __HIP_MEMORY_SCOPE_AGENT);
}
__device__ __forceinline__ void st_llc4f(float* p, float v) {
    __hip_atomic_store(p, v, __ATOMIC_RELAXED, __HIP_MEMORY_SCOPE_AGENT);
}
__device__ __forceinline__ float ld_llc4f(const float* p) {
    return __hip_atomic_load(p, __ATOMIC_RELAXED, __HIP_MEMORY_SCOPE_AGENT);
}

// ---------------------------------------------------------------------------
// init: pack W_ih/W_hh into LDS-slice layout [cg][kb][gate][lane][8] bf16,
// W_out into [nt][kb][lane][8], zero hpack slot0 and the barrier page.
// ---------------------------------------------------------------------------
__global__ void gru_init(const float* __restrict__ W_ih, const float* __restrict__ W_hh,
                         const float* __restrict__ W_out,
                         ushort_t* __restrict__ wpack, ushort_t* __restrict__ wopack,
                         ushort_t* __restrict__ hpack0, uint_t* __restrict__ bar)
{
    const int total = NWPACK + NWOPACK + HPACK_SLOT/2 + 1024;
    for (int e = blockIdx.x * 256 + threadIdx.x; e < total; e += gridDim.x * 256) {
        if (e < NWPACK) {
            int j = e & 7;
            int lane = (e >> 3) & 63;
            int t2 = e >> 9;
            int g  = t2 % 3;
            int t3 = t2 / 3;
            int kb = t3 % 40;
            int cg = t3 / 40;
            int n = g * 1024 + cg * 16 + (lane & 15);
            int koff = ((lane >> 4) << 3) + j;
            float v;
            if (kb < 8) v = W_ih[(size_t)n * 256 + kb * 32 + koff];
            else        v = W_hh[(size_t)n * 1024 + (kb - 8) * 32 + koff];
            wpack[e] = f2bf(v);
        } else if (e < NWPACK + NWOPACK) {
            int e2 = e - NWPACK;
            int j = e2 & 7;
            int lane = (e2 >> 3) & 63;
            int kb = (e2 >> 9) & 31;
            int nt = e2 >> 14;
            int n = nt * 16 + (lane & 15);
            int k = kb * 32 + ((lane >> 4) << 3) + j;
            wopack[e2] = f2bf(W_out[(size_t)n * 1024 + k]);
        } else if (e < NWPACK + NWOPACK + HPACK_SLOT/2) {
            ((uint_t*)hpack0)[e - NWPACK - NWOPACK] = 0u;
        } else {
            bar[e - NWPACK - NWOPACK - HPACK_SLOT/2] = 0u;
        }
    }
}

// ---------------------------------------------------------------------------
// per-group barrier (64 WGs): monotone arrival counter, relaxed atomics only.
// Data ordering: __syncthreads() emits s_waitcnt vmcnt(0) before s_barrier,
// so every wave's sc1 stores are LLC-acked before thread 0 issues the RMW.
// ---------------------------------------------------------------------------
__device__ __forceinline__ void group_barrier(uint_t* bar, int grp, uint_t target)
{
    __syncthreads();
    if (threadIdx.x == 0) {
        uint_t* cnt = bar + grp * 64;
        uint_t* gen = bar + grp * 64 + 32;
        uint_t a = __hip_atomic_fetch_add(cnt, 1u, __ATOMIC_RELAXED, __HIP_MEMORY_SCOPE_AGENT);
        if (a == (target << 6) - 1u) {
            __hip_atomic_fetch_add(gen, 1u, __ATOMIC_RELAXED, __HIP_MEMORY_SCOPE_AGENT);
        } else {
            while (__hip_atomic_load(gen, __ATOMIC_RELAXED, __HIP_MEMORY_SCOPE_AGENT) < target)
                __builtin_amdgcn_s_sleep(1);
        }
    }
    __syncthreads();
}

// ---------------------------------------------------------------------------
// main persistent kernel
// ---------------------------------------------------------------------------
__global__ void __launch_bounds__(256, 1)
gru_main(const float* __restrict__ seq,
         const float* __restrict__ b_ih, const float* __restrict__ b_hh,
         const float* __restrict__ b_out,
         const ushort_t* __restrict__ wpack, const ushort_t* __restrict__ wopack,
         ushort_t* __restrict__ hpack, float* __restrict__ outpart,
         uint_t* __restrict__ bar, float* __restrict__ dout)
{
    extern __shared__ char lds[];
    ushort_t* wlds = (ushort_t*)lds;            // [40][3][64][8] bf16 = 122880 B
    float*    xch  = (float*)(lds + 122880);    // [4][2][4][64][4] f32 = 32768 B

    const int b   = blockIdx.x;
    const int grp = (b & 7) >> 1;                 // batch group 0..3 (2 XCDs under rr)
    const int id  = ((b >> 3) << 1) | (b & 1);    // 0..63 within group
    const int cg  = id;                           // h-column group (16 cols)
    const int m   = grp;                          // batch slice (32 rows)
    const int tid = threadIdx.x;
    const int wv  = tid >> 6;
    const int ln  = tid & 63;

    // stage this WG's weight slice into LDS (coalesced 16B)
    {
        const uint4* src = (const uint4*)(wpack + (size_t)cg * 61440);
        uint4* dst = (uint4*)lds;
        for (int i = tid; i < 7680; i += 256) dst[i] = src[i];
    }

    float bihr = 0, bhhr = 0, bihz = 0, bhhz = 0, bihn = 0, bhhn = 0;
    if (wv < 2) {
        int col = cg * 16 + (ln & 15);
        bihr = b_ih[col];          bhhr = b_hh[col];
        bihz = b_ih[1024 + col];   bhhz = b_hh[1024 + col];
        bihn = b_ih[2048 + col];   bhhn = b_hh[2048 + col];
    }
    const float bo0 = b_out[ln], bo1 = b_out[ln + 64];

    floatx4 hold = {0.f, 0.f, 0.f, 0.f};   // fp32 authoritative h slice (reducers)

    // out-projection job for this WG (within its group)
    const int omt = 2 * grp + (id & 1);     // m-tile 0..7
    const int ont = (id >> 1) & 7;          // out col tile 0..7
    const int oks = (id >> 4) & 3;          // k-split 0..3 (8 kb each)
    const int kb0 = wv * 10;
    const int mtb0 = m * 2, mtb1 = m * 2 + 1;

    __syncthreads();

#define XSLOT(sw, mt, g) (xch + (((sw) * 2 + (mt)) * 4 + (g)) * 256 + ln * 4)

    for (int it = 0; it < 1025; ++it) {
        const ushort_t* hcur = hpack + (size_t)(it & 3) * HPACK_SLOT;

        floatx4 accr0 = {0,0,0,0}, accr1 = {0,0,0,0};
        floatx4 accz0 = {0,0,0,0}, accz1 = {0,0,0,0};
        floatx4 acch0 = {0,0,0,0}, acch1 = {0,0,0,0};
        floatx4 acci0 = {0,0,0,0}, acci1 = {0,0,0,0};

        if (it <= 1022) {
            #pragma unroll
            for (int ki = 0; ki < 10; ++ki) {
                const int kb = kb0 + ki;
                bf16x8 a0, a1;
                if (kb < 8) {
                    // x_t fp32 -> bf16 on the fly (A-frag layout); seq stays L2-cached
                    int koffx = kb * 32 + ((ln >> 4) << 3);
                    const float* p0 = seq + (size_t)(mtb0 * 16 + (ln & 15)) * (T_ * I_)
                                          + (size_t)it * I_ + koffx;
                    const float* p1 = p0 + (size_t)16 * (T_ * I_);
                    float4 fa = *(const float4*)p0, fb = *(const float4*)(p0 + 4);
                    float4 ga = *(const float4*)p1, gb = *(const float4*)(p1 + 4);
                    ushortx8 u0, u1;
                    u0[0] = f2bf(fa.x); u0[1] = f2bf(fa.y); u0[2] = f2bf(fa.z); u0[3] = f2bf(fa.w);
                    u0[4] = f2bf(fb.x); u0[5] = f2bf(fb.y); u0[6] = f2bf(fb.z); u0[7] = f2bf(fb.w);
                    u1[0] = f2bf(ga.x); u1[1] = f2bf(ga.y); u1[2] = f2bf(ga.z); u1[3] = f2bf(ga.w);
                    u1[4] = f2bf(gb.x); u1[5] = f2bf(gb.y); u1[6] = f2bf(gb.z); u1[7] = f2bf(gb.w);
                    a0 = __builtin_bit_cast(bf16x8, u0);
                    a1 = __builtin_bit_cast(bf16x8, u1);
                } else {
                    a0 = ld_llc16(hcur + (((size_t)mtb0 * 32 + (kb - 8)) * 64 + ln) * 8);
                    a1 = ld_llc16(hcur + (((size_t)mtb1 * 32 + (kb - 8)) * 64 + ln) * 8);
                }
                const bf16x8 br = *(const bf16x8*)(wlds + ((kb * 3 + 0) * 64 + ln) * 8);
                const bf16x8 bz = *(const bf16x8*)(wlds + ((kb * 3 + 1) * 64 + ln) * 8);
                const bf16x8 bn = *(const bf16x8*)(wlds + ((kb * 3 + 2) * 64 + ln) * 8);
                accr0 = mfma16(a0, br, accr0);  accr1 = mfma16(a1, br, accr1);
                accz0 = mfma16(a0, bz, accz0);  accz1 = mfma16(a1, bz, accz1);
                if (kb < 8) { acci0 = mfma16(a0, bn, acci0); acci1 = mfma16(a1, bn, acci1); }
                else        { acch0 = mfma16(a0, bn, acch0); acch1 = mfma16(a1, bn, acch1); }
            }
            // exchange partial accumulators via LDS
            if (wv == 0) {
                *(floatx4*)XSLOT(0, 1, 0) = accr1; *(floatx4*)XSLOT(0, 1, 1) = accz1;
                *(floatx4*)XSLOT(0, 1, 2) = acch1; *(floatx4*)XSLOT(0, 1, 3) = acci1;
            } else if (wv == 1) {
                *(floatx4*)XSLOT(1, 0, 0) = accr0; *(floatx4*)XSLOT(1, 0, 1) = accz0;
                *(floatx4*)XSLOT(1, 0, 2) = acch0;
            } else {
                *(floatx4*)XSLOT(wv, 0, 0) = accr0; *(floatx4*)XSLOT(wv, 0, 1) = accz0;
                *(floatx4*)XSLOT(wv, 0, 2) = acch0;
                *(floatx4*)XSLOT(wv, 1, 0) = accr1; *(floatx4*)XSLOT(wv, 1, 1) = accz1;
                *(floatx4*)XSLOT(wv, 1, 2) = acch1;
            }
        }
        __syncthreads();

        // reducers: gate math, h update (fp32 regs), write bf16 hpack (sc1)
        if (it <= 1022 && wv < 2) {
            const int mtr = wv;
            floatx4 r  = (mtr == 0) ? accr0 : accr1;
            floatx4 z  = (mtr == 0) ? accz0 : accz1;
            floatx4 hn = (mtr == 0) ? acch0 : acch1;
            floatx4 inn = (wv == 0) ? acci0 : *(floatx4*)XSLOT(0, 1, 3);
            #pragma unroll
            for (int sw = 0; sw < 4; ++sw) {
                if (sw == wv) continue;
                r  += *(floatx4*)XSLOT(sw, mtr, 0);
                z  += *(floatx4*)XSLOT(sw, mtr, 1);
                hn += *(floatx4*)XSLOT(sw, mtr, 2);
            }
            ushort_t* hnew = hpack + (size_t)((it + 1) & 3) * HPACK_SLOT;
            const int mtW = m * 2 + mtr;
            const int kbh = cg >> 1;
            const int koffb = ((cg & 1) << 4) + (ln & 15);
            const int lanep = (koffb >> 3) << 4;
            const int jj = koffb & 7;
            const int rbase = (ln >> 4) * 4;
            #pragma unroll
            for (int e = 0; e < 4; ++e) {
                float rp = r[e] + bihr + bhhr;
                float rg = 1.f / (1.f + __expf(-rp));
                float zp = z[e] + bihz + bhhz;
                float zg = 1.f / (1.f + __expf(-zp));
                float nx = inn[e] + bihn + rg * (hn[e] + bhhn);
                float ng = 1.f - 2.f / (__expf(2.f * nx) + 1.f);
                float hv = (1.f - zg) * ng + zg * hold[e];
                hold[e] = hv;
                size_t idx = (((size_t)mtW * 32 + kbh) * 64 + (unsigned)((rbase + e) | lanep)) * 8 + jj;
                st_llc2(&hnew[idx], f2bf(hv));
            }
        }

        // wave2: out-projection partial for h_it (one step behind gates)
        if (wv == 2 && it >= 1 && it <= 1023) {
            const ushort_t* hh = hpack + (size_t)(it & 3) * HPACK_SLOT;
            floatx4 acc = {0, 0, 0, 0};
            #pragma unroll
            for (int i2 = 0; i2 < 8; ++i2) {
                int kb = oks * 8 + i2;
                bf16x8 a = ld_llc16(hh + (((size_t)omt * 32 + kb) * 64 + ln) * 8);
                bf16x8 bb = *(const bf16x8*)(wopack + (((size_t)ont * 32 + kb) * 64 + ln) * 8);
                acc = mfma16(a, bb, acc);
            }
            float* op = outpart + (size_t)(it & 1) * 65536 + (size_t)oks * 16384;
            int colo = ont * 16 + (ln & 15);
            #pragma unroll
            for (int e = 0; e < 4; ++e) {
                int rowo = omt * 16 + (ln >> 4) * 4 + e;
                st_llc4f(op + rowo * 128 + colo, acc[e]);
            }
        }

        // wave3: finalize log_softmax for h_{it-1} (two steps behind gates)
        if (wv == 3 && id < 32 && it >= 2) {
            const float* op = outpart + (size_t)((it - 1) & 1) * 65536;
            const int row = grp * 32 + id;
            float v0 = bo0, v1 = bo1;
            #pragma unroll
            for (int ks2 = 0; ks2 < 4; ++ks2) {
                v0 += ld_llc4f(op + ks2 * 16384 + row * 128 + ln);
                v1 += ld_llc4f(op + ks2 * 16384 + row * 128 + ln + 64);
            }
            float mx = fmaxf(v0, v1);
            #pragma unroll
            for (int off = 32; off >= 1; off >>= 1) mx = fmaxf(mx, __shfl_xor(mx, off));
            float e0 = __expf(v0 - mx), e1 = __expf(v1 - mx);
            float sm = e0 + e1;
            #pragma unroll
            for (int off = 32; off >= 1; off >>= 1) sm += __shfl_xor(sm, off);
            float lse = mx + __logf(sm);
            float* po = dout + ((size_t)row * 1023 + (it - 2)) * 128;
            po[ln] = v0 - lse;
            po[ln + 64] = v1 - lse;
        }

        if (it < 1024) group_barrier(bar, grp, (uint_t)(it + 1));
    }
#undef XSLOT
}

// ---------------------------------------------------------------------------
extern "C" void kernel_launch(void* const* d_in, const int* in_sizes, int n_in,
                              void* d_out, int out_size, void* d_ws, size_t ws_size,
                              hipStream_t stream)
{
    const float* seq  = (const float*)d_in[0];
    const float* Wih  = (const float*)d_in[1];
    const float* Whh  = (const float*)d_in[2];
    const float* bih  = (const float*)d_in[3];
    const float* bhh  = (const float*)d_in[4];
    const float* Wout = (const float*)d_in[5];
    const float* bout = (const float*)d_in[6];

    char* ws = (char*)d_ws;
    ushort_t* wpack   = (ushort_t*)(ws + WPACK_OFF);
    ushort_t* wopack  = (ushort_t*)(ws + WOPACK_OFF);
    ushort_t* hpack   = (ushort_t*)(ws + HPACK_OFF);
    float*    outpart = (float*)(ws + OUTPART_OFF);
    uint_t*   bar     = (uint_t*)(ws + BAR_OFF);

    gru_init<<<1024, 256, 0, stream>>>(Wih, Whh, Wout, wpack, wopack, hpack, bar);

    hipFuncSetAttribute((const void*)gru_main,
                        hipFuncAttributeMaxDynamicSharedMemorySize, 155648);
    gru_main<<<256, 256, 155648, stream>>>(seq, bih, bhh, bout, wpack, wopack,
                                           hpack, outpart, bar, (float*)d_out);
}